// Round 23
// baseline (136.649 us; speedup 1.0000x reference)
//
#include <hip/hip_runtime.h>
#include <cfloat>

#define N_TOK   32768
#define DIM     64
#define K_CODES 8192
#define NCHK    64                 // 128-code chunks
#define TPB     128                // tokens per select block

#define IDX_OFF  (N_TOK * DIM)
#define LOSS_OFF (N_TOK * DIM + N_TOK)

// ---- fallback (R20) ws layout, float units ----
#define WS_ESQ   0
#define WS_EHIT  8192
#define WS_PART  270336            // 128 floats
// fallback out-region scratch: eT at out+0 (524288 f), Mm at out+524288 (2M ushorts)

// ---- fused ws layout, float units ----
#define W2_ESQ   0
#define W2_EHIT  8192              // 524288 ushorts = 262144 float slots
#define W2_ET    270336            // 524288 floats
#define W2_MM    794624            // 2097152 ushorts = 1048576 float slots
#define W2_PART  1843200           // 256 floats
#define W2_TOTAL 1843456           // floats -> 7,373,824 bytes

#define MRG   2e-5f     // strict slack: bound < every computed fl-d in chunk

typedef __attribute__((ext_vector_type(8)))  short bf16x8;
typedef __attribute__((ext_vector_type(16))) float f32x16;

__device__ inline ushort f2bf(float x) {          // round-to-nearest-even
    unsigned u = __float_as_uint(x);
    return (ushort)((u + 0x7FFFu + ((u >> 16) & 1u)) >> 16);
}
__device__ inline float bf2f(ushort h) { return __uint_as_float(((unsigned)h) << 16); }
__device__ inline ushort f2bf_up(float x) {       // round toward +inf (conservative)
    unsigned u = __float_as_uint(x);
    return (x >= 0.0f) ? (ushort)((u + 0xFFFFu) >> 16) : (ushort)(u >> 16);
}
// sortable pack: lexicographic (d, idx) min == np argmin first-occurrence
__device__ inline unsigned long long packdi(float d, int i) {
    unsigned u = __float_as_uint(d);
    u ^= (u & 0x80000000u) ? 0xFFFFFFFFu : 0x80000000u;
    return ((unsigned long long)u << 32) | (unsigned)i;
}
__device__ inline float unpackd(unsigned long long k) {   // exact inverse (d part)
    unsigned u = (unsigned)(k >> 32);
    u = (u & 0x80000000u) ? (u ^ 0x80000000u) : ~u;
    return __uint_as_float(u);
}

// ---------------------------------------------------------------------------
// e_sq[k] = numpy-pairwise sum of squares (bitwise np order) — proven R1-R22.
// ---------------------------------------------------------------------------
__global__ __launch_bounds__(256) void esq_kernel(const float* __restrict__ emb,
                                                  float* __restrict__ esq) {
#pragma clang fp contract(off)
    const int tid = threadIdx.x;
    const int q = tid & 7;
    const int code = blockIdx.x * 32 + (tid >> 3);
    const float* row = emb + code * DIM;
    float x = row[q];
    float r = x * x;
#pragma unroll
    for (int m = 1; m < 8; ++m) {
        float y = row[q + 8 * m];
        float sq = y * y;
        r = r + sq;
    }
    r = r + __shfl_xor(r, 1, 64);
    r = r + __shfl_xor(r, 2, 64);
    r = r + __shfl_xor(r, 4, 64);
    if (q == 0) esq[code] = r;
}

// ---------------------------------------------------------------------------
// Pack: ehiT = bf16 e in MFMA-A-fragment order; eT = exact f32 transpose.
// ---------------------------------------------------------------------------
__global__ __launch_bounds__(256) void pack2(const float* __restrict__ emb,
                                             ushort* __restrict__ ehiT,
                                             float* __restrict__ eT) {
#pragma clang fp contract(off)
    const int k = blockIdx.x * 256 + threadIdx.x;   // 8192 codes
    float v[64];
    {
        const float4* ep = (const float4*)(emb + (size_t)k * DIM);
#pragma unroll
        for (int i = 0; i < 16; ++i) {
            const float4 a = ep[i];
            v[4 * i] = a.x; v[4 * i + 1] = a.y; v[4 * i + 2] = a.z; v[4 * i + 3] = a.w;
        }
    }
#pragma unroll
    for (int j = 0; j < 64; ++j) eT[(size_t)j * K_CODES + k] = v[j];
    const int sc = k >> 7, lc = k & 127;
#pragma unroll
    for (int q = 0; q < 4; ++q)
#pragma unroll
        for (int h = 0; h < 2; ++h) {
            bf16x8 o;
#pragma unroll
            for (int e = 0; e < 8; ++e) o[e] = (short)f2bf(v[16 * q + 8 * h + e]);
            *(bf16x8*)(ehiT + ((((size_t)sc * 4 + q) * 2 + h) * 128 + lc) * 8) = o;
        }
}

// ---------------------------------------------------------------------------
// MFMA sweep v4 (unchanged from R20/R22, passed): z_hi only, g-level A dbuf.
// ---------------------------------------------------------------------------
__global__ __launch_bounds__(256, 2) void vq_mfma(const float* __restrict__ hid,
                                                  const ushort* __restrict__ ehiT,
                                                  ushort* __restrict__ Mm) {
#pragma clang fp contract(off)
    const int tid = threadIdx.x;
    const int lane = tid & 63;
    const int w = tid >> 6;
    const int h = lane >> 5;
    const int t0 = blockIdx.x * 64;

    bf16x8 z_hi[2][4];
#pragma unroll
    for (int ts = 0; ts < 2; ++ts)
#pragma unroll
    for (int q = 0; q < 4; ++q) {
        const float* zp = hid + (size_t)(t0 + 32 * ts + (lane & 31)) * DIM + 16 * q + 8 * h;
        const float4 u0 = *(const float4*)zp;
        const float4 u1 = *(const float4*)(zp + 4);
        const float zz[8] = {u0.x, u0.y, u0.z, u0.w, u1.x, u1.y, u1.z, u1.w};
        bf16x8 hv;
#pragma unroll
        for (int i = 0; i < 8; ++i) hv[i] = (short)f2bf(zz[i]);
        z_hi[ts][q] = hv;
    }

    f32x16 zc;
#pragma unroll
    for (int i = 0; i < 16; ++i) zc[i] = 0.0f;

#define ALOAD(SC, R, Q) (*(const bf16x8*)(ehiT + \
    ((((size_t)(SC) * 4 + (Q)) * 2 + h) * 128 + 32 * (R) + (lane & 31)) * 8))

    bf16x8 Aa[4][4], Ab[4][4];
#pragma unroll
    for (int r = 0; r < 4; ++r)
#pragma unroll
        for (int q = 0; q < 4; ++q) Aa[r][q] = ALOAD(w, r, q);

#define MFMA_G(CUR, NXT, G) { \
    const int sc = 4 * (G) + w; \
    const int scn = ((G) + 1 < 16) ? (4 * ((G) + 1) + w) : sc; \
    _Pragma("unroll") \
    for (int r = 0; r < 4; ++r) \
        _Pragma("unroll") \
        for (int q = 0; q < 4; ++q) NXT[r][q] = ALOAD(scn, r, q); \
    float wm0 = -3.0e38f, wm1 = -3.0e38f; \
    _Pragma("unroll") \
    for (int r = 0; r < 4; ++r) { \
        f32x16 d0 = __builtin_amdgcn_mfma_f32_32x32x16_bf16(CUR[r][0], z_hi[0][0], zc, 0, 0, 0); \
        f32x16 d1 = __builtin_amdgcn_mfma_f32_32x32x16_bf16(CUR[r][0], z_hi[1][0], zc, 0, 0, 0); \
        _Pragma("unroll") \
        for (int q = 1; q < 4; ++q) { \
            d0 = __builtin_amdgcn_mfma_f32_32x32x16_bf16(CUR[r][q], z_hi[0][q], d0, 0, 0, 0); \
            d1 = __builtin_amdgcn_mfma_f32_32x32x16_bf16(CUR[r][q], z_hi[1][q], d1, 0, 0, 0); \
        } \
        _Pragma("unroll") \
        for (int i = 0; i < 16; ++i) { \
            wm0 = fmaxf(wm0, d0[i]); \
            wm1 = fmaxf(wm1, d1[i]); \
        } \
    } \
    wm0 = fmaxf(wm0, __shfl_xor(wm0, 32, 64)); \
    wm1 = fmaxf(wm1, __shfl_xor(wm1, 32, 64)); \
    if (lane < 32) { \
        Mm[(size_t)sc * N_TOK + t0 + lane]      = f2bf_up(wm0); \
        Mm[(size_t)sc * N_TOK + t0 + 32 + lane] = f2bf_up(wm1); \
    } }

    for (int gg = 0; gg < 16; gg += 2) {
        MFMA_G(Aa, Ab, gg)
        MFMA_G(Ab, Aa, gg + 1)
    }
#undef MFMA_G
#undef ALOAD
}

// ---------------------------------------------------------------------------
// Paired pipelined chunk eval (R16/R20/R22-proven, bitwise chains): lane owns
// 2 codes of chunk c; 2 tokens share one e-stream; atomicMin (d,idx) fold.
// ---------------------------------------------------------------------------
__device__ __forceinline__ void eval_chunk(const int c,
                                           unsigned long long msk0,
                                           unsigned long long msk1,
                                           const float* __restrict__ eT,
                                           const float* __restrict__ esq,
                                           const float (*z_s)[68],
                                           const float* zsq_s,
                                           unsigned long long* key_s,
                                           const int lane) {
#pragma clang fp contract(off)
    if (!(msk0 | msk1)) return;
    const int k0 = c * 128 + 2 * lane;
    const float* eb = eT + k0;
    const float2 es2 = *(const float2*)(esq + k0);

    while (msk0 | msk1) {
        int G = 1;
        int tA, tB;
        if (msk0) { tA = __ffsll(msk0) - 1; msk0 &= msk0 - 1; }
        else      { tA = 64 + __ffsll(msk1) - 1; msk1 &= msk1 - 1; }
        tB = tA;
        if (msk0 | msk1) {
            G = 2;
            if (msk0) { tB = __ffsll(msk0) - 1; msk0 &= msk0 - 1; }
            else      { tB = 64 + __ffsll(msk1) - 1; msk1 &= msk1 - 1; }
        }
        const float4* zpA = (const float4*)(&z_s[tA][0]);
        const float4* zpB = (const float4*)(&z_s[tB][0]);

        float2 bA[8], bB[8];
        float aA0, aA1, aB0, aB1;
#define LOADG(B, G2) { _Pragma("unroll") \
    for (int j = 0; j < 8; ++j) \
        B[j] = *(const float2*)(eb + (size_t)(8 * (G2) + j) * K_CODES); }
#define FMAJ(Bj, vA, vB, COMP) \
    aA0 = fmaf(vA.COMP, Bj.x, aA0); aA1 = fmaf(vA.COMP, Bj.y, aA1); \
    aB0 = fmaf(vB.COMP, Bj.x, aB0); aB1 = fmaf(vB.COMP, Bj.y, aB1);
#define FMAG(B, G2) { \
    const float4 vA = zpA[2 * (G2)], vB = zpB[2 * (G2)]; \
    FMAJ(B[0], vA, vB, x) FMAJ(B[1], vA, vB, y) \
    FMAJ(B[2], vA, vB, z) FMAJ(B[3], vA, vB, w) \
    const float4 uA = zpA[2 * (G2) + 1], uB = zpB[2 * (G2) + 1]; \
    FMAJ(B[4], uA, uB, x) FMAJ(B[5], uA, uB, y) \
    FMAJ(B[6], uA, uB, z) FMAJ(B[7], uA, uB, w) }

        LOADG(bA, 0)
        LOADG(bB, 1)
        {   // group 0, j=0 peeled as mul (bitwise head of each chain)
            const float4 vA = zpA[0], vB = zpB[0];
            aA0 = vA.x * bA[0].x; aA1 = vA.x * bA[0].y;
            aB0 = vB.x * bA[0].x; aB1 = vB.x * bA[0].y;
            FMAJ(bA[1], vA, vB, y)
            FMAJ(bA[2], vA, vB, z)
            FMAJ(bA[3], vA, vB, w)
            const float4 uA = zpA[1], uB = zpB[1];
            FMAJ(bA[4], uA, uB, x)
            FMAJ(bA[5], uA, uB, y)
            FMAJ(bA[6], uA, uB, z)
            FMAJ(bA[7], uA, uB, w)
        }
        LOADG(bA, 2) FMAG(bB, 1)
        LOADG(bB, 3) FMAG(bA, 2)
        LOADG(bA, 4) FMAG(bB, 3)
        LOADG(bB, 5) FMAG(bA, 4)
        LOADG(bA, 6) FMAG(bB, 5)
        LOADG(bB, 7) FMAG(bA, 6)
        FMAG(bB, 7)
#undef LOADG
#undef FMAJ
#undef FMAG

#define FINISH(aX0, aX1, tX) { \
    const float zqX = zsq_s[tX]; \
    const float dX0 = fmaf(-2.0f, aX0, zqX + es2.x); \
    const float dX1 = fmaf(-2.0f, aX1, zqX + es2.y); \
    float dl = dX0; int il = k0; \
    if (dX1 < dl) { dl = dX1; il = k0 + 1; } \
    _Pragma("unroll") \
    for (int mm = 1; mm < 64; mm <<= 1) { \
        const float ov = __shfl_xor(dl, mm, 64); \
        const int   oi = __shfl_xor(il, mm, 64); \
        if (ov < dl || (ov == dl && oi < il)) { dl = ov; il = oi; } \
    } \
    if (lane == 0) atomicMin(&key_s[tX], packdi(dl, il)); }

        FINISH(aA0, aA1, tA)
        if (G > 1) FINISH(aB0, aB1, tB)
#undef FINISH
    }
}

// ---------------------------------------------------------------------------
// Select v12: two-stage pruning. Stage A: eval each token's argmax chunk
// (partition masks — 1 item/token, no bound). Then bD = exact evaluated d
// (unpacked from key). Stage B: bound-screen remaining chunks against exact
// bD (2.5x tighter window than the old init bound; DINIT gone). Pruned
// chunks: all d strictly > bD >= final best -> no lost ties. FUSED=1 adds
// the proven vq_finish epilogue.
// ---------------------------------------------------------------------------
template <int FUSED>
__global__ __launch_bounds__(512, 1) void vq_select_t(const float* __restrict__ hid,
                                                      const float* __restrict__ eT,
                                                      const float* __restrict__ esq,
                                                      const ushort* __restrict__ Mm,
                                                      const float* __restrict__ emb,
                                                      float* __restrict__ out_zq,
                                                      float* __restrict__ out_idx,
                                                      float* __restrict__ partials) {
#pragma clang fp contract(off)
    __shared__ float z_s[TPB][68];
    __shared__ float zsq_s[TPB];
    __shared__ float eps_s[TPB];
    __shared__ float bD_s[TPB];
    __shared__ float mxw[4][TPB];
    __shared__ int   cw[4][TPB];
    __shared__ int   cstar_s[TPB];
    __shared__ unsigned long long key_s[TPB];
    __shared__ float lred[2];

    const int tid = threadIdx.x;
    const int lane = tid & 63;
    const int w = tid >> 6;                 // 0..7
    const int t0 = blockIdx.x * TPB;

    // ---- stage z into LDS; init keys ----
    {
        const int t = tid >> 2;                // 0..127
        const int j4 = (tid & 3) * 4;          // float4 index (4 per thread)
        const float4* src = (const float4*)(hid + (size_t)(t0 + t) * DIM);
        float4* dst = (float4*)(&z_s[t][0]);
#pragma unroll
        for (int i = 0; i < 4; ++i) dst[j4 + i] = src[j4 + i];
    }
    if (tid < TPB) key_s[tid] = ~0ull;
    __syncthreads();

    // ---- phase 1a: partial Mm-argmax (512 workers) + zsq (threads 0..127) ----
    {
        const int token = tid & 127;
        const int cg = tid >> 7;               // 0..3
        const int c0 = 16 * cg;
        float pm = bf2f(Mm[(size_t)c0 * N_TOK + t0 + token]);
        int   pc = c0;
#pragma unroll 5
        for (int c = c0 + 1; c < c0 + 16; ++c) {
            const float v = bf2f(Mm[(size_t)c * N_TOK + t0 + token]);
            if (v > pm) { pm = v; pc = c; }
        }
        mxw[cg][token] = pm;
        cw[cg][token] = pc;
    }
    if (tid < TPB) {
        const float* zr = &z_s[tid][0];
        float r[8];
#pragma unroll
        for (int q = 0; q < 8; ++q) {
            float x = zr[q]; r[q] = x * x;
#pragma unroll
            for (int m = 1; m < 8; ++m) {
                float y = zr[q + 8 * m];
                float sq = y * y;
                r[q] = r[q] + sq;
            }
        }
        zsq_s[tid] = ((r[0] + r[1]) + (r[2] + r[3])) + ((r[4] + r[5]) + (r[6] + r[7]));
    }
    __syncthreads();
    if (tid < TPB) {
        float mx = mxw[0][tid]; int cst = cw[0][tid];
#pragma unroll
        for (int g = 1; g < 4; ++g)
            if (mxw[g][tid] > mx) { mx = mxw[g][tid]; cst = cw[g][tid]; }
        cstar_s[tid] = cst;
        eps_s[tid] = sqrtf(zsq_s[tid]) * 4.2e-6f + 2e-7f;   // e-bf16 + z-bf16 (no lo)
    }
    __syncthreads();

    // ---- stage A: eval each token's argmax chunk (partition; 1 item/token) ----
    for (int i = 0; i < 8; ++i) {
        const int c = 8 * w + i;
        const unsigned long long m0 = __ballot(cstar_s[lane] == c);
        const unsigned long long m1 = __ballot(cstar_s[64 + lane] == c);
        eval_chunk(c, m0, m1, eT, esq, z_s, zsq_s, key_s, lane);
    }
    __syncthreads();
    if (tid < TPB) bD_s[tid] = unpackd(key_s[tid]);   // exact achieved best d
    __syncthreads();

    // ---- stage B: bound-screen vs exact bD; eval survivors ----
    for (int i = 0; i < 8; ++i) {
        const int c = 8 * w + i;
        const float mA = bf2f(Mm[(size_t)c * N_TOK + t0 + lane]);
        const int sA = ((fmaf(-2.0f, mA + eps_s[lane], zsq_s[lane]) - MRG) < bD_s[lane])
                       && (cstar_s[lane] != c);
        const unsigned long long m0 = __ballot(sA);
        const float mB = bf2f(Mm[(size_t)c * N_TOK + t0 + 64 + lane]);
        const int sB = ((fmaf(-2.0f, mB + eps_s[64 + lane], zsq_s[64 + lane]) - MRG) < bD_s[64 + lane])
                       && (cstar_s[64 + lane] != c);
        const unsigned long long m1 = __ballot(sB);
        eval_chunk(c, m0, m1, eT, esq, z_s, zsq_s, key_s, lane);
    }
    __syncthreads();

    if (FUSED) {
        // ---- fused vq_finish epilogue (per-token chain byte-identical) ----
        if (tid < TPB) {
            const int t = t0 + tid;
            const int bi = (int)(key_s[tid] & 0xFFFFFFFFull);
            out_idx[t] = (float)bi;
            const float4* q4 = (const float4*)(emb + (size_t)bi * DIM);
            const float4* h4 = (const float4*)(&z_s[tid][0]);   // same bits as hid row
            float4* o4 = (float4*)(out_zq + (size_t)t * DIM);
            float lsum = 0.f;
#pragma unroll
            for (int i = 0; i < 16; ++i) {
                const float4 q = q4[i];
                const float4 h = h4[i];
                float4 zq;
                float dx;
                dx = q.x - h.x; zq.x = h.x + dx; lsum += dx * dx;
                dx = q.y - h.y; zq.y = h.y + dx; lsum += dx * dx;
                dx = q.z - h.z; zq.z = h.z + dx; lsum += dx * dx;
                dx = q.w - h.w; zq.w = h.w + dx; lsum += dx * dx;
                o4[i] = zq;
            }
#pragma unroll
            for (int off = 32; off >= 1; off >>= 1) lsum += __shfl_xor(lsum, off, 64);
            if ((tid & 63) == 0) lred[tid >> 6] = lsum;
        }
        __syncthreads();
        if (tid == 0) partials[blockIdx.x] = lred[0] + lred[1];
    } else {
        if (tid < TPB) out_idx[t0 + tid] = (float)(int)(key_s[tid] & 0xFFFFFFFFull);
    }
}

// ---------------------------------------------------------------------------
// Fallback outputs kernel (proven vq_finish) + both loss reducers.
// ---------------------------------------------------------------------------
__global__ __launch_bounds__(256) void vq_finish(const float* __restrict__ hid,
                                                 const float* __restrict__ emb,
                                                 const float* __restrict__ out_idx,
                                                 float* __restrict__ out_zq,
                                                 float* __restrict__ partials) {
#pragma clang fp contract(off)
    __shared__ float lred[4];
    const int tid = threadIdx.x;
    const int t = blockIdx.x * 256 + tid;

    const int bi = (int)out_idx[t];

    const float4* q4 = (const float4*)(emb + (size_t)bi * DIM);
    const float4* h4 = (const float4*)(hid + (size_t)t * DIM);
    float4* o4 = (float4*)(out_zq + (size_t)t * DIM);
    float lsum = 0.f;
#pragma unroll
    for (int i = 0; i < 16; ++i) {
        const float4 q = q4[i];
        const float4 h = h4[i];
        float4 zq;
        float dx;
        dx = q.x - h.x; zq.x = h.x + dx; lsum += dx * dx;
        dx = q.y - h.y; zq.y = h.y + dx; lsum += dx * dx;
        dx = q.z - h.z; zq.z = h.z + dx; lsum += dx * dx;
        dx = q.w - h.w; zq.w = h.w + dx; lsum += dx * dx;
        o4[i] = zq;
    }

#pragma unroll
    for (int off = 32; off >= 1; off >>= 1) lsum += __shfl_xor(lsum, off, 64);
    const int wid = tid >> 6;
    if ((tid & 63) == 0) lred[wid] = lsum;
    __syncthreads();
    if (tid == 0) partials[blockIdx.x] = (lred[0] + lred[1]) + (lred[2] + lred[3]);
}

__global__ __launch_bounds__(128) void loss_kernel128(const float* __restrict__ partials,
                                                      float* __restrict__ out_loss) {
#pragma clang fp contract(off)
    __shared__ float s[128];
    const int t = threadIdx.x;
    s[t] = partials[t];
    __syncthreads();
    for (int off = 64; off >= 1; off >>= 1) {
        if (t < off) s[t] = s[t] + s[t + off];
        __syncthreads();
    }
    if (t == 0) {
        const float m = s[0] * (1.0f / 2097152.0f);  // exact: /2^21
        out_loss[0] = m + 0.25f * m;
    }
}

__global__ __launch_bounds__(128) void loss_kernel256(const float* __restrict__ partials,
                                                      float* __restrict__ out_loss) {
#pragma clang fp contract(off)
    __shared__ float s[128];
    const int t = threadIdx.x;
    s[t] = partials[t] + partials[t + 128];
    __syncthreads();
    for (int off = 64; off >= 1; off >>= 1) {
        if (t < off) s[t] = s[t] + s[t + off];
        __syncthreads();
    }
    if (t == 0) {
        const float m = s[0] * (1.0f / 2097152.0f);  // exact: /2^21
        out_loss[0] = m + 0.25f * m;
    }
}

extern "C" void kernel_launch(void* const* d_in, const int* in_sizes, int n_in,
                              void* d_out, int out_size, void* d_ws, size_t ws_size,
                              hipStream_t stream) {
    const float* hid = (const float*)d_in[0];
    const float* emb = (const float*)d_in[1];
    float* out = (float*)d_out;
    float* ws  = (float*)d_ws;

    if (ws_size >= (size_t)W2_TOTAL * sizeof(float)) {
        // ---- fused path: eT/Mm in ws; select writes zq/idx/loss partials ----
        float*  esq   = ws + W2_ESQ;
        ushort* ehiT  = (ushort*)(ws + W2_EHIT);
        float*  eT    = ws + W2_ET;
        ushort* Mm    = (ushort*)(ws + W2_MM);
        float*  parts = ws + W2_PART;

        esq_kernel<<<K_CODES / 32, 256, 0, stream>>>(emb, esq);
        pack2<<<K_CODES / 256, 256, 0, stream>>>(emb, ehiT, eT);
        vq_mfma<<<N_TOK / 64, 256, 0, stream>>>(hid, ehiT, Mm);
        vq_select_t<1><<<N_TOK / TPB, 512, 0, stream>>>(hid, eT, esq, Mm, emb,
                                                        out, out + IDX_OFF, parts);
        loss_kernel256<<<1, 128, 0, stream>>>(parts, out + LOSS_OFF);
    } else {
        // ---- fallback path: R20 structure ----
        float*  esq   = ws + WS_ESQ;
        ushort* ehiT  = (ushort*)(ws + WS_EHIT);
        float*  parts = ws + WS_PART;
        float*  eT    = out;                               // zq-region scratch
        ushort* Mm    = (ushort*)(out + 524288);           // zq-region scratch

        esq_kernel<<<K_CODES / 32, 256, 0, stream>>>(emb, esq);
        pack2<<<K_CODES / 256, 256, 0, stream>>>(emb, ehiT, eT);
        vq_mfma<<<N_TOK / 64, 256, 0, stream>>>(hid, ehiT, Mm);
        vq_select_t<0><<<N_TOK / TPB, 512, 0, stream>>>(hid, eT, esq, Mm, emb,
                                                        out, out + IDX_OFF, parts);
        vq_finish<<<N_TOK / 256, 256, 0, stream>>>(hid, emb, out + IDX_OFF, out, parts);
        loss_kernel128<<<1, 128, 0, stream>>>(parts, out + LOSS_OFF);
    }
}

// Round 24
// 128.603 us; speedup vs baseline: 1.0626x; 1.0626x over previous
//
#include <hip/hip_runtime.h>
#include <cfloat>

#define N_TOK   32768
#define DIM     64
#define K_CODES 8192
#define NCHK    128                // 64-code chunks
#define TPB     128                // tokens per select block

#define IDX_OFF  (N_TOK * DIM)
#define LOSS_OFF (N_TOK * DIM + N_TOK)

// ---- fallback ws layout, float units (ws >= 7.37MB proven engaged in R22) ----
#define WS_ESQ   0
#define WS_EHIT  8192              // 524288 ushorts
#define WS_ET    270336            // 524288 floats
#define WS_PART  794624            // 128 floats
// fallback: Mm = out zq region (4194304 ushorts = 8388608 B, exact fit)

// ---- fused ws layout, float units ----
#define W2_ESQ   0
#define W2_EHIT  8192
#define W2_ET    270336
#define W2_MM    794624            // 4194304 ushorts = 2097152 float slots
#define W2_PART  2891776           // 256 floats
#define W2_TOTAL 2892032           // floats -> 11,568,128 bytes

#define MRG   2e-5f     // strict slack: bound < every computed fl-d in chunk
#define DINIT 6e-5f     // init slack (proven R14-R22; mx bit-identical at fine grain)

typedef __attribute__((ext_vector_type(8)))  short bf16x8;
typedef __attribute__((ext_vector_type(16))) float f32x16;

__device__ inline ushort f2bf(float x) {          // round-to-nearest-even
    unsigned u = __float_as_uint(x);
    return (ushort)((u + 0x7FFFu + ((u >> 16) & 1u)) >> 16);
}
__device__ inline float bf2f(ushort h) { return __uint_as_float(((unsigned)h) << 16); }
__device__ inline ushort f2bf_up(float x) {       // round toward +inf (conservative)
    unsigned u = __float_as_uint(x);
    return (x >= 0.0f) ? (ushort)((u + 0xFFFFu) >> 16) : (ushort)(u >> 16);
}
// sortable pack: lexicographic (d, idx) min == np argmin first-occurrence
__device__ inline unsigned long long packdi(float d, int i) {
    unsigned u = __float_as_uint(d);
    u ^= (u & 0x80000000u) ? 0xFFFFFFFFu : 0x80000000u;
    return ((unsigned long long)u << 32) | (unsigned)i;
}

// ---------------------------------------------------------------------------
// e_sq[k] = numpy-pairwise sum of squares (bitwise np order) — proven R1-R23.
// ---------------------------------------------------------------------------
__global__ __launch_bounds__(256) void esq_kernel(const float* __restrict__ emb,
                                                  float* __restrict__ esq) {
#pragma clang fp contract(off)
    const int tid = threadIdx.x;
    const int q = tid & 7;
    const int code = blockIdx.x * 32 + (tid >> 3);
    const float* row = emb + code * DIM;
    float x = row[q];
    float r = x * x;
#pragma unroll
    for (int m = 1; m < 8; ++m) {
        float y = row[q + 8 * m];
        float sq = y * y;
        r = r + sq;
    }
    r = r + __shfl_xor(r, 1, 64);
    r = r + __shfl_xor(r, 2, 64);
    r = r + __shfl_xor(r, 4, 64);
    if (q == 0) esq[code] = r;
}

// ---------------------------------------------------------------------------
// Pack: ehiT = bf16 e in MFMA-A-fragment order; eT = exact f32 transpose.
// ---------------------------------------------------------------------------
__global__ __launch_bounds__(256) void pack2(const float* __restrict__ emb,
                                             ushort* __restrict__ ehiT,
                                             float* __restrict__ eT) {
#pragma clang fp contract(off)
    const int k = blockIdx.x * 256 + threadIdx.x;   // 8192 codes
    float v[64];
    {
        const float4* ep = (const float4*)(emb + (size_t)k * DIM);
#pragma unroll
        for (int i = 0; i < 16; ++i) {
            const float4 a = ep[i];
            v[4 * i] = a.x; v[4 * i + 1] = a.y; v[4 * i + 2] = a.z; v[4 * i + 3] = a.w;
        }
    }
#pragma unroll
    for (int j = 0; j < 64; ++j) eT[(size_t)j * K_CODES + k] = v[j];
    const int sc = k >> 7, lc = k & 127;
#pragma unroll
    for (int q = 0; q < 4; ++q)
#pragma unroll
        for (int h = 0; h < 2; ++h) {
            bf16x8 o;
#pragma unroll
            for (int e = 0; e < 8; ++e) o[e] = (short)f2bf(v[16 * q + 8 * h + e]);
            *(bf16x8*)(ehiT + ((((size_t)sc * 4 + q) * 2 + h) * 128 + lc) * 8) = o;
        }
}

// ---------------------------------------------------------------------------
// MFMA sweep v5: v4's proven structure (z_hi only, g-level A dbuf); wm
// reduced per r-PAIR -> two 64-code fine-chunk maxes per 128-code sweep.
// Mm[fine_chunk][token], bf16-up. Fine chunk 2sc covers codes sc*128+[0,64).
// ---------------------------------------------------------------------------
__global__ __launch_bounds__(256, 2) void vq_mfma(const float* __restrict__ hid,
                                                  const ushort* __restrict__ ehiT,
                                                  ushort* __restrict__ Mm) {
#pragma clang fp contract(off)
    const int tid = threadIdx.x;
    const int lane = tid & 63;
    const int w = tid >> 6;
    const int h = lane >> 5;
    const int t0 = blockIdx.x * 64;

    bf16x8 z_hi[2][4];
#pragma unroll
    for (int ts = 0; ts < 2; ++ts)
#pragma unroll
    for (int q = 0; q < 4; ++q) {
        const float* zp = hid + (size_t)(t0 + 32 * ts + (lane & 31)) * DIM + 16 * q + 8 * h;
        const float4 u0 = *(const float4*)zp;
        const float4 u1 = *(const float4*)(zp + 4);
        const float zz[8] = {u0.x, u0.y, u0.z, u0.w, u1.x, u1.y, u1.z, u1.w};
        bf16x8 hv;
#pragma unroll
        for (int i = 0; i < 8; ++i) hv[i] = (short)f2bf(zz[i]);
        z_hi[ts][q] = hv;
    }

    f32x16 zc;
#pragma unroll
    for (int i = 0; i < 16; ++i) zc[i] = 0.0f;

#define ALOAD(SC, R, Q) (*(const bf16x8*)(ehiT + \
    ((((size_t)(SC) * 4 + (Q)) * 2 + h) * 128 + 32 * (R) + (lane & 31)) * 8))

    bf16x8 Aa[4][4], Ab[4][4];
#pragma unroll
    for (int r = 0; r < 4; ++r)
#pragma unroll
        for (int q = 0; q < 4; ++q) Aa[r][q] = ALOAD(w, r, q);

#define MFMA_HALF(CUR, R0, WM0, WM1) { \
    _Pragma("unroll") \
    for (int r = (R0); r < (R0) + 2; ++r) { \
        f32x16 d0 = __builtin_amdgcn_mfma_f32_32x32x16_bf16(CUR[r][0], z_hi[0][0], zc, 0, 0, 0); \
        f32x16 d1 = __builtin_amdgcn_mfma_f32_32x32x16_bf16(CUR[r][0], z_hi[1][0], zc, 0, 0, 0); \
        _Pragma("unroll") \
        for (int q = 1; q < 4; ++q) { \
            d0 = __builtin_amdgcn_mfma_f32_32x32x16_bf16(CUR[r][q], z_hi[0][q], d0, 0, 0, 0); \
            d1 = __builtin_amdgcn_mfma_f32_32x32x16_bf16(CUR[r][q], z_hi[1][q], d1, 0, 0, 0); \
        } \
        _Pragma("unroll") \
        for (int i = 0; i < 16; ++i) { \
            WM0 = fmaxf(WM0, d0[i]); \
            WM1 = fmaxf(WM1, d1[i]); \
        } \
    } }

#define MFMA_G(CUR, NXT, G) { \
    const int sc = 4 * (G) + w; \
    const int scn = ((G) + 1 < 16) ? (4 * ((G) + 1) + w) : sc; \
    _Pragma("unroll") \
    for (int r = 0; r < 4; ++r) \
        _Pragma("unroll") \
        for (int q = 0; q < 4; ++q) NXT[r][q] = ALOAD(scn, r, q); \
    float wma0 = -3.0e38f, wma1 = -3.0e38f, wmb0 = -3.0e38f, wmb1 = -3.0e38f; \
    MFMA_HALF(CUR, 0, wma0, wma1) \
    MFMA_HALF(CUR, 2, wmb0, wmb1) \
    wma0 = fmaxf(wma0, __shfl_xor(wma0, 32, 64)); \
    wma1 = fmaxf(wma1, __shfl_xor(wma1, 32, 64)); \
    wmb0 = fmaxf(wmb0, __shfl_xor(wmb0, 32, 64)); \
    wmb1 = fmaxf(wmb1, __shfl_xor(wmb1, 32, 64)); \
    if (lane < 32) { \
        Mm[(size_t)(2 * sc) * N_TOK + t0 + lane]          = f2bf_up(wma0); \
        Mm[(size_t)(2 * sc) * N_TOK + t0 + 32 + lane]     = f2bf_up(wma1); \
        Mm[(size_t)(2 * sc + 1) * N_TOK + t0 + lane]      = f2bf_up(wmb0); \
        Mm[(size_t)(2 * sc + 1) * N_TOK + t0 + 32 + lane] = f2bf_up(wmb1); \
    } }

    for (int gg = 0; gg < 16; gg += 2) {
        MFMA_G(Aa, Ab, gg)
        MFMA_G(Ab, Aa, gg + 1)
    }
#undef MFMA_G
#undef MFMA_HALF
#undef ALOAD
}

// ---------------------------------------------------------------------------
// Paired pipelined 64-code chunk eval: lane owns ONE code; 2 tokens share
// one e-stream. Chains byte-identical form (peeled j=0 mul + sequential
// fmaf). atomicMin (d,idx) fold into key_s.
// ---------------------------------------------------------------------------
__device__ __forceinline__ void eval_chunk64(const int c,
                                             unsigned long long msk0,
                                             unsigned long long msk1,
                                             const float* __restrict__ eT,
                                             const float* __restrict__ esq,
                                             const float (*z_s)[68],
                                             const float* zsq_s,
                                             unsigned long long* key_s,
                                             const int lane) {
#pragma clang fp contract(off)
    if (!(msk0 | msk1)) return;
    const int k0 = c * 64 + lane;
    const float* eb = eT + k0;
    const float es1 = esq[k0];

    while (msk0 | msk1) {
        int G = 1;
        int tA, tB;
        if (msk0) { tA = __ffsll(msk0) - 1; msk0 &= msk0 - 1; }
        else      { tA = 64 + __ffsll(msk1) - 1; msk1 &= msk1 - 1; }
        tB = tA;
        if (msk0 | msk1) {
            G = 2;
            if (msk0) { tB = __ffsll(msk0) - 1; msk0 &= msk0 - 1; }
            else      { tB = 64 + __ffsll(msk1) - 1; msk1 &= msk1 - 1; }
        }
        const float4* zpA = (const float4*)(&z_s[tA][0]);
        const float4* zpB = (const float4*)(&z_s[tB][0]);

        float bA[8], bB[8];
        float aA0, aB0;
#define LOADG(B, G2) { _Pragma("unroll") \
    for (int j = 0; j < 8; ++j) \
        B[j] = eb[(size_t)(8 * (G2) + j) * K_CODES]; }
#define FMAG(B, G2) { \
    const float4 vA = zpA[2 * (G2)], vB = zpB[2 * (G2)]; \
    aA0 = fmaf(vA.x, B[0], aA0); aB0 = fmaf(vB.x, B[0], aB0); \
    aA0 = fmaf(vA.y, B[1], aA0); aB0 = fmaf(vB.y, B[1], aB0); \
    aA0 = fmaf(vA.z, B[2], aA0); aB0 = fmaf(vB.z, B[2], aB0); \
    aA0 = fmaf(vA.w, B[3], aA0); aB0 = fmaf(vB.w, B[3], aB0); \
    const float4 uA = zpA[2 * (G2) + 1], uB = zpB[2 * (G2) + 1]; \
    aA0 = fmaf(uA.x, B[4], aA0); aB0 = fmaf(uB.x, B[4], aB0); \
    aA0 = fmaf(uA.y, B[5], aA0); aB0 = fmaf(uB.y, B[5], aB0); \
    aA0 = fmaf(uA.z, B[6], aA0); aB0 = fmaf(uB.z, B[6], aB0); \
    aA0 = fmaf(uA.w, B[7], aA0); aB0 = fmaf(uB.w, B[7], aB0); }

        LOADG(bA, 0)
        LOADG(bB, 1)
        {   // group 0, j=0 peeled as mul (bitwise head of each chain)
            const float4 vA = zpA[0], vB = zpB[0];
            aA0 = vA.x * bA[0]; aB0 = vB.x * bA[0];
            aA0 = fmaf(vA.y, bA[1], aA0); aB0 = fmaf(vB.y, bA[1], aB0);
            aA0 = fmaf(vA.z, bA[2], aA0); aB0 = fmaf(vB.z, bA[2], aB0);
            aA0 = fmaf(vA.w, bA[3], aA0); aB0 = fmaf(vB.w, bA[3], aB0);
            const float4 uA = zpA[1], uB = zpB[1];
            aA0 = fmaf(uA.x, bA[4], aA0); aB0 = fmaf(uB.x, bA[4], aB0);
            aA0 = fmaf(uA.y, bA[5], aA0); aB0 = fmaf(uB.y, bA[5], aB0);
            aA0 = fmaf(uA.z, bA[6], aA0); aB0 = fmaf(uB.z, bA[6], aB0);
            aA0 = fmaf(uA.w, bA[7], aA0); aB0 = fmaf(uB.w, bA[7], aB0);
        }
        LOADG(bA, 2) FMAG(bB, 1)
        LOADG(bB, 3) FMAG(bA, 2)
        LOADG(bA, 4) FMAG(bB, 3)
        LOADG(bB, 5) FMAG(bA, 4)
        LOADG(bA, 6) FMAG(bB, 5)
        LOADG(bB, 7) FMAG(bA, 6)
        FMAG(bB, 7)
#undef LOADG
#undef FMAG

#define FINISH(aX0, tX) { \
    float dl = fmaf(-2.0f, aX0, zsq_s[tX] + es1); \
    int il = k0; \
    _Pragma("unroll") \
    for (int mm = 1; mm < 64; mm <<= 1) { \
        const float ov = __shfl_xor(dl, mm, 64); \
        const int   oi = __shfl_xor(il, mm, 64); \
        if (ov < dl || (ov == dl && oi < il)) { dl = ov; il = oi; } \
    } \
    if (lane == 0) atomicMin(&key_s[tX], packdi(dl, il)); }

        FINISH(aA0, tA)
        if (G > 1) FINISH(aB0, tB)
#undef FINISH
    }
}

// ---------------------------------------------------------------------------
// Select v13: R22's proven single-stage structure at 64-code granularity.
// 8 waves; wave w owns chunks [16w,16w+16). FUSED=1 adds vq_finish epilogue.
// ---------------------------------------------------------------------------
template <int FUSED>
__global__ __launch_bounds__(512, 1) void vq_select_t(const float* __restrict__ hid,
                                                      const float* __restrict__ eT,
                                                      const float* __restrict__ esq,
                                                      const ushort* __restrict__ Mm,
                                                      const float* __restrict__ emb,
                                                      float* __restrict__ out_zq,
                                                      float* __restrict__ out_idx,
                                                      float* __restrict__ partials) {
#pragma clang fp contract(off)
    __shared__ float z_s[TPB][68];
    __shared__ float zsq_s[TPB];
    __shared__ float eps_s[TPB];
    __shared__ float bD_s[TPB];
    __shared__ float mxw[4][TPB];
    __shared__ unsigned long long key_s[TPB];
    __shared__ unsigned long long m0_s[NCHK];
    __shared__ unsigned long long m1_s[NCHK];
    __shared__ float lred[2];

    const int tid = threadIdx.x;
    const int lane = tid & 63;
    const int w = tid >> 6;                 // 0..7
    const int t0 = blockIdx.x * TPB;

    // ---- stage z into LDS; init keys ----
    {
        const int t = tid >> 2;                // 0..127
        const int j4 = (tid & 3) * 4;          // float4 index (4 per thread)
        const float4* src = (const float4*)(hid + (size_t)(t0 + t) * DIM);
        float4* dst = (float4*)(&z_s[t][0]);
#pragma unroll
        for (int i = 0; i < 4; ++i) dst[j4 + i] = src[j4 + i];
    }
    if (tid < TPB) key_s[tid] = ~0ull;
    __syncthreads();

    // ---- phase 1a: partial Mm-max (512 workers, 32 chunks each) + zsq ----
    {
        const int token = tid & 127;
        const int cg = tid >> 7;               // 0..3
        const int c0 = 32 * cg;
        float pm = bf2f(Mm[(size_t)c0 * N_TOK + t0 + token]);
#pragma unroll 8
        for (int c = c0 + 1; c < c0 + 32; ++c)
            pm = fmaxf(pm, bf2f(Mm[(size_t)c * N_TOK + t0 + token]));
        mxw[cg][token] = pm;
    }
    if (tid < TPB) {
        const float* zr = &z_s[tid][0];
        float r[8];
#pragma unroll
        for (int q = 0; q < 8; ++q) {
            float x = zr[q]; r[q] = x * x;
#pragma unroll
            for (int m = 1; m < 8; ++m) {
                float y = zr[q + 8 * m];
                float sq = y * y;
                r[q] = r[q] + sq;
            }
        }
        zsq_s[tid] = ((r[0] + r[1]) + (r[2] + r[3])) + ((r[4] + r[5]) + (r[6] + r[7]));
    }
    __syncthreads();
    if (tid < TPB) {
        const float mx = fmaxf(fmaxf(mxw[0][tid], mxw[1][tid]),
                               fmaxf(mxw[2][tid], mxw[3][tid]));
        const float zsq = zsq_s[tid];
        const float eps = sqrtf(zsq) * 4.2e-6f + 2e-7f;   // e-bf16 + z-bf16 (no lo)
        eps_s[tid] = eps;
        bD_s[tid] = zsq - 2.0f * mx + 2.0f * eps + DINIT;   // >= true best fl-d
    }
    __syncthreads();

    // ---- phase 1b: survivor masks for this wave's 16 chunks (ballot) ----
#pragma unroll
    for (int i = 0; i < 16; ++i) {
        const int c = 16 * w + i;
        const float mA = bf2f(Mm[(size_t)c * N_TOK + t0 + lane]);
        const int sA = (fmaf(-2.0f, mA + eps_s[lane], zsq_s[lane]) - MRG) < bD_s[lane];
        const unsigned long long b0 = __ballot(sA);
        const float mB = bf2f(Mm[(size_t)c * N_TOK + t0 + 64 + lane]);
        const int sB = (fmaf(-2.0f, mB + eps_s[64 + lane], zsq_s[64 + lane]) - MRG) < bD_s[64 + lane];
        const unsigned long long b1 = __ballot(sB);
        if (lane == 0) { m0_s[c] = b0; m1_s[c] = b1; }
    }
    // no barrier: each wave reads only masks it wrote

    // ---- phase 2: paired eval over this wave's 16 chunks ----
    for (int i = 0; i < 16; ++i) {
        const int c = 16 * w + i;
        eval_chunk64(c, m0_s[c], m1_s[c], eT, esq, z_s, zsq_s, key_s, lane);
    }
    __syncthreads();

    if (FUSED) {
        // ---- fused vq_finish epilogue (per-token chain byte-identical) ----
        if (tid < TPB) {
            const int t = t0 + tid;
            const int bi = (int)(key_s[tid] & 0xFFFFFFFFull);
            out_idx[t] = (float)bi;
            const float4* q4 = (const float4*)(emb + (size_t)bi * DIM);
            const float4* h4 = (const float4*)(&z_s[tid][0]);   // same bits as hid row
            float4* o4 = (float4*)(out_zq + (size_t)t * DIM);
            float lsum = 0.f;
#pragma unroll
            for (int i = 0; i < 16; ++i) {
                const float4 q = q4[i];
                const float4 h = h4[i];
                float4 zq;
                float dx;
                dx = q.x - h.x; zq.x = h.x + dx; lsum += dx * dx;
                dx = q.y - h.y; zq.y = h.y + dx; lsum += dx * dx;
                dx = q.z - h.z; zq.z = h.z + dx; lsum += dx * dx;
                dx = q.w - h.w; zq.w = h.w + dx; lsum += dx * dx;
                o4[i] = zq;
            }
#pragma unroll
            for (int off = 32; off >= 1; off >>= 1) lsum += __shfl_xor(lsum, off, 64);
            if ((tid & 63) == 0) lred[tid >> 6] = lsum;
        }
        __syncthreads();
        if (tid == 0) partials[blockIdx.x] = lred[0] + lred[1];
    } else {
        if (tid < TPB) out_idx[t0 + tid] = (float)(int)(key_s[tid] & 0xFFFFFFFFull);
    }
}

// ---------------------------------------------------------------------------
// Fallback outputs kernel (proven vq_finish) + both loss reducers.
// ---------------------------------------------------------------------------
__global__ __launch_bounds__(256) void vq_finish(const float* __restrict__ hid,
                                                 const float* __restrict__ emb,
                                                 const float* __restrict__ out_idx,
                                                 float* __restrict__ out_zq,
                                                 float* __restrict__ partials) {
#pragma clang fp contract(off)
    __shared__ float lred[4];
    const int tid = threadIdx.x;
    const int t = blockIdx.x * 256 + tid;

    const int bi = (int)out_idx[t];

    const float4* q4 = (const float4*)(emb + (size_t)bi * DIM);
    const float4* h4 = (const float4*)(hid + (size_t)t * DIM);
    float4* o4 = (float4*)(out_zq + (size_t)t * DIM);
    float lsum = 0.f;
#pragma unroll
    for (int i = 0; i < 16; ++i) {
        const float4 q = q4[i];
        const float4 h = h4[i];
        float4 zq;
        float dx;
        dx = q.x - h.x; zq.x = h.x + dx; lsum += dx * dx;
        dx = q.y - h.y; zq.y = h.y + dx; lsum += dx * dx;
        dx = q.z - h.z; zq.z = h.z + dx; lsum += dx * dx;
        dx = q.w - h.w; zq.w = h.w + dx; lsum += dx * dx;
        o4[i] = zq;
    }

#pragma unroll
    for (int off = 32; off >= 1; off >>= 1) lsum += __shfl_xor(lsum, off, 64);
    const int wid = tid >> 6;
    if ((tid & 63) == 0) lred[wid] = lsum;
    __syncthreads();
    if (tid == 0) partials[blockIdx.x] = (lred[0] + lred[1]) + (lred[2] + lred[3]);
}

__global__ __launch_bounds__(128) void loss_kernel128(const float* __restrict__ partials,
                                                      float* __restrict__ out_loss) {
#pragma clang fp contract(off)
    __shared__ float s[128];
    const int t = threadIdx.x;
    s[t] = partials[t];
    __syncthreads();
    for (int off = 64; off >= 1; off >>= 1) {
        if (t < off) s[t] = s[t] + s[t + off];
        __syncthreads();
    }
    if (t == 0) {
        const float m = s[0] * (1.0f / 2097152.0f);  // exact: /2^21
        out_loss[0] = m + 0.25f * m;
    }
}

__global__ __launch_bounds__(128) void loss_kernel256(const float* __restrict__ partials,
                                                      float* __restrict__ out_loss) {
#pragma clang fp contract(off)
    __shared__ float s[128];
    const int t = threadIdx.x;
    s[t] = partials[t] + partials[t + 128];
    __syncthreads();
    for (int off = 64; off >= 1; off >>= 1) {
        if (t < off) s[t] = s[t] + s[t + off];
        __syncthreads();
    }
    if (t == 0) {
        const float m = s[0] * (1.0f / 2097152.0f);  // exact: /2^21
        out_loss[0] = m + 0.25f * m;
    }
}

extern "C" void kernel_launch(void* const* d_in, const int* in_sizes, int n_in,
                              void* d_out, int out_size, void* d_ws, size_t ws_size,
                              hipStream_t stream) {
    const float* hid = (const float*)d_in[0];
    const float* emb = (const float*)d_in[1];
    float* out = (float*)d_out;
    float* ws  = (float*)d_ws;

    if (ws_size >= (size_t)W2_TOTAL * sizeof(float)) {
        // ---- fused path: everything in ws; select writes zq/idx/partials ----
        float*  esq   = ws + W2_ESQ;
        ushort* ehiT  = (ushort*)(ws + W2_EHIT);
        float*  eT    = ws + W2_ET;
        ushort* Mm    = (ushort*)(ws + W2_MM);
        float*  parts = ws + W2_PART;

        esq_kernel<<<K_CODES / 32, 256, 0, stream>>>(emb, esq);
        pack2<<<K_CODES / 256, 256, 0, stream>>>(emb, ehiT, eT);
        vq_mfma<<<N_TOK / 64, 256, 0, stream>>>(hid, ehiT, Mm);
        vq_select_t<1><<<N_TOK / TPB, 512, 0, stream>>>(hid, eT, esq, Mm, emb,
                                                        out, out + IDX_OFF, parts);
        loss_kernel256<<<1, 128, 0, stream>>>(parts, out + LOSS_OFF);
    } else {
        // ---- fallback: Mm in the dead zq region (exact 8 MB fit); eT in ws ----
        float*  esq   = ws + WS_ESQ;
        ushort* ehiT  = (ushort*)(ws + WS_EHIT);
        float*  eT    = ws + WS_ET;
        float*  parts = ws + WS_PART;
        ushort* Mm    = (ushort*)out;

        esq_kernel<<<K_CODES / 32, 256, 0, stream>>>(emb, esq);
        pack2<<<K_CODES / 256, 256, 0, stream>>>(emb, ehiT, eT);
        vq_mfma<<<N_TOK / 64, 256, 0, stream>>>(hid, ehiT, Mm);
        vq_select_t<0><<<N_TOK / TPB, 512, 0, stream>>>(hid, eT, esq, Mm, emb,
                                                        out, out + IDX_OFF, parts);
        vq_finish<<<N_TOK / 256, 256, 0, stream>>>(hid, emb, out + IDX_OFF, out, parts);
        loss_kernel128<<<1, 128, 0, stream>>>(parts, out + LOSS_OFF);
    }
}